// Round 10
// baseline (698.959 us; speedup 1.0000x reference)
//
#include <hip/hip_runtime.h>
#include <cfloat>

#define K_NUM 512
#define C_DIM 256

// workspace float offsets — small fixed region first, private tables last
#define WS_CNT    0          // [512] cluster counts
#define WS_ESQ    512        // [512] ||e_k||^2
#define WS_SMOOTH 1024       // [512] smoothed cluster size
#define WS_LOSS   1536       // [1] (+pad)
#define WS_CBT    2048       // [256][512] transposed codebook
#define WS_ACC    133120     // nblk x [512][256] private embed-sum tables

// output float offsets (z_q, vq_loss, indices, new_codebook, new_cluster_size, new_embed_sum)
#define OFF_LOSS 16777216
#define OFF_IDX  16777217
#define OFF_CB   16842753
#define OFF_CS   16973825
#define OFF_ES   16974337

// async global->LDS, 16B per lane (dest linear in lane order)
__device__ __forceinline__ void gl_lds16(const float* g, float* l) {
  __builtin_amdgcn_global_load_lds(
      (const __attribute__((address_space(1))) unsigned int*)g,
      (__attribute__((address_space(3))) unsigned int*)l, 16, 0, 0);
}

// ---------- kernel 0a: e_sq + zero counts/loss ----------
__global__ __launch_bounds__(256) void k0a_prep(const float* __restrict__ cb,
                                                float* __restrict__ ws) {
  int k = blockIdx.x, c = threadIdx.x;
  float v = cb[k * C_DIM + c];
  float s = v * v;
  #pragma unroll
  for (int o = 32; o > 0; o >>= 1) s += __shfl_down(s, o, 64);
  __shared__ float ls[4];
  if ((c & 63) == 0) ls[c >> 6] = s;
  __syncthreads();
  if (c == 0) {
    ws[WS_ESQ + k] = ls[0] + ls[1] + ls[2] + ls[3];
    ws[WS_CNT + k] = 0.f;
    if (k == 0) ws[WS_LOSS] = 0.f;
  }
}

// ---------- kernel 0b: codebook transpose [k][c] -> [c][k] (LDS-tiled) ----------
__global__ __launch_bounds__(256) void k0b_transpose(const float* __restrict__ cb,
                                                     float* __restrict__ cbT) {
  __shared__ float t[64 * 69];
  int tid = threadIdx.x;
  int k0 = (blockIdx.x >> 2) * 64;
  int c0 = (blockIdx.x & 3) * 64;
  {
    int kk = tid >> 4, cq = tid & 15;
    #pragma unroll
    for (int r = 0; r < 4; ++r) {
      int row = kk + 16 * r;
      float4 v = *(const float4*)&cb[(size_t)(k0 + row) * C_DIM + c0 + 4 * cq];
      float* p = &t[row * 69 + 4 * cq];
      p[0] = v.x; p[1] = v.y; p[2] = v.z; p[3] = v.w;
    }
  }
  __syncthreads();
  {
    int kq = tid & 15, cc = tid >> 4;
    #pragma unroll
    for (int r = 0; r < 4; ++r) {
      int c = cc + 16 * r;
      float4 v;
      v.x = t[(4 * kq + 0) * 69 + c];
      v.y = t[(4 * kq + 1) * 69 + c];
      v.z = t[(4 * kq + 2) * 69 + c];
      v.w = t[(4 * kq + 3) * 69 + c];
      *(float4*)&cbT[(size_t)(c0 + c) * K_NUM + k0 + 4 * kq] = v;
    }
  }
}

// stage one 16c x 128k codebook tile into ct buffer (2 x 16B per thread)
#define STAGE_CT(buf, skc, sc8) do {                                          \
    int c0_ = (sc8) << 4;                                                     \
    _Pragma("unroll")                                                         \
    for (int r_ = 0; r_ < 2; ++r_) {                                          \
      int i4_ = tid + (r_ << 8);                                              \
      gl_lds16(cbT + ((size_t)(c0_ + (i4_ >> 5)) << 9) + ((skc) << 7)         \
                   + ((i4_ & 31) << 2),                                       \
               &ct[((buf) << 11) + (i4_ << 2)]);                              \
    }                                                                         \
  } while (0)

// ---------- k1: distance-GEMM + argmin + z_q + loss ----------
// grid 512 x 256. Block: 128 consecutive n (fixed b,d), all 512 k.
// Whole z-slice (128 KB) staged ONCE in LDS; 8 KB codebook tiles double-buffered
// via global_load_lds (L2-hot). Thread tile 8n x 8k. 1 block/CU.
__global__ __launch_bounds__(256) void k1_gemm(const float* __restrict__ z,
                                               const float* __restrict__ cb,
                                               float* __restrict__ out,
                                               float* __restrict__ ws) {
  __shared__ __align__(16) float zt[256 * 128];    // z slice [c][n]  (128 KB)
  __shared__ __align__(16) float ct[2 * 16 * 128]; // 2 x 16c x 128k  (16 KB)
  __shared__ __align__(16) int   s_fidx[128];
  __shared__ float s_fmv[128];
  __shared__ float s_ls[4];

  const float* cbT = ws + WS_CBT;
  const float* esq = ws + WS_ESQ;

  int tid = threadIdx.x;
  int nb = blockIdx.x << 7;          // n base
  int b = nb >> 12;
  int d = (nb >> 8) & 15;
  int off = nb & 255;
  size_t base = (size_t)b * 1048576 + (size_t)d * 256 + off;  // + c*4096 + j
  const float* zbase = z + base;

  int wn = tid >> 4;   // [0,16): 8-n group
  int wk = tid & 15;   // [0,16): 8-k group

  // stage entire z slice: 256c x 128n = 8192 x 16B chunks, 32 per thread
  #pragma unroll 8
  for (int r = 0; r < 32; ++r) {
    int idx4 = tid + (r << 8);             // chunk id in [0, 8192)
    gl_lds16(zbase + ((size_t)(idx4 >> 5) << 12) + ((idx4 & 31) << 2),
             &zt[idx4 << 2]);
  }
  STAGE_CT(0, 0, 0);
  __syncthreads();   // drains vmcnt + barrier

  float minv[8]; int mini[8];
  #pragma unroll
  for (int i = 0; i < 8; ++i) { minv[i] = FLT_MAX; mini[i] = 0; }

  int cur = 0;
  for (int kc = 0; kc < 4; ++kc) {   // 4 k-chunks of 128
    float acc[8][8];
    #pragma unroll
    for (int i = 0; i < 8; ++i)
      #pragma unroll
      for (int j = 0; j < 8; ++j) acc[i][j] = 0.f;

    for (int c8 = 0; c8 < 16; ++c8) { // 16 c-chunks of 16
      int nc8 = c8 + 1, nkc = kc + (nc8 >> 4); nc8 &= 15;
      if (nkc < 4) STAGE_CT(cur ^ 1, nkc, nc8);   // prefetch next tile
      const float* ctb = &ct[cur << 11];
      #pragma unroll 4
      for (int cc = 0; cc < 16; ++cc) {
        int c = (c8 << 4) + cc;
        float4 za = *(const float4*)&zt[c * 128 + 4 * wn];       // 16-lane bcast
        float4 zb = *(const float4*)&zt[c * 128 + 64 + 4 * wn];
        float4 ca = *(const float4*)&ctb[cc * 128 + 4 * wk];     // 2-way: free
        float4 cb4 = *(const float4*)&ctb[cc * 128 + 64 + 4 * wk];
        float zr[8] = {za.x, za.y, za.z, za.w, zb.x, zb.y, zb.z, zb.w};
        float cr[8] = {ca.x, ca.y, ca.z, ca.w, cb4.x, cb4.y, cb4.z, cb4.w};
        #pragma unroll
        for (int i = 0; i < 8; ++i)
          #pragma unroll
          for (int j = 0; j < 8; ++j) acc[i][j] += zr[i] * cr[j];
      }
      __syncthreads();   // next tile landed (vmcnt) + all waves done reading
      cur ^= 1;
    }
    // running lexicographic min with val = e^2 - 2*dot (z^2 is a per-n shift)
    #pragma unroll
    for (int j = 0; j < 8; ++j) {
      int kg = kc * 128 + (j >> 2) * 64 + 4 * wk + (j & 3);
      float er = esq[kg];
      #pragma unroll
      for (int i = 0; i < 8; ++i) {
        float val = er - 2.f * acc[i][j];
        if (val < minv[i] || (val == minv[i] && kg < mini[i])) { minv[i] = val; mini[i] = kg; }
      }
    }
  }
  // in-register argmin reduce across the 16 wk lanes (lex butterfly, width 16)
  #pragma unroll
  for (int i = 0; i < 8; ++i) {
    float v = minv[i]; int ii = mini[i];
    #pragma unroll
    for (int o = 8; o > 0; o >>= 1) {
      float ov = __shfl_xor(v, o, 16);
      int   oi = __shfl_xor(ii, o, 16);
      if (ov < v || (ov == v && oi < ii)) { v = ov; ii = oi; }
    }
    if (wk == i) {
      int n = (i >> 2) * 64 + 4 * wn + (i & 3);
      s_fidx[n] = ii; s_fmv[n] = v;
      out[OFF_IDX + nb + n] = (float)ii;
    }
  }
  __syncthreads();
  // phase 3: z_q gather-write + z^2 for loss; z read from LDS (no global re-read)
  int j4 = (tid & 31) * 4;   // n offset
  int ch = tid >> 5;         // c residue 0..7
  int4 idxs = *(const int4*)&s_fidx[j4];
  const float* r0 = cb + (size_t)idxs.x * C_DIM;
  const float* r1 = cb + (size_t)idxs.y * C_DIM;
  const float* r2 = cb + (size_t)idxs.z * C_DIM;
  const float* r3 = cb + (size_t)idxs.w * C_DIM;
  float zsq = 0.f;
  #pragma unroll 4
  for (int i = 0; i < 32; ++i) {
    int c = ch + 8 * i;
    float4 zv = *(const float4*)&zt[c * 128 + j4];
    float4 q = make_float4(r0[c], r1[c], r2[c], r3[c]);
    *(float4*)(out + base + (size_t)c * 4096 + j4) = q;
    zsq += zv.x * zv.x + zv.y * zv.y + zv.z * zv.z + zv.w * zv.w;
  }
  if (tid < 128) zsq += s_fmv[tid];   // ||z-e||^2 = z^2 + (e^2 - 2 dot)
  #pragma unroll
  for (int o = 32; o > 0; o >>= 1) zsq += __shfl_down(zsq, o, 64);
  if ((tid & 63) == 0) s_ls[tid >> 6] = zsq;
  __syncthreads();
  if (tid == 0) unsafeAtomicAdd(&ws[WS_LOSS], s_ls[0] + s_ls[1] + s_ls[2] + s_ls[3]);
}

// ---------- k1b: embed-sum via LDS tables, native ds_add_f32 ----------
// grid nblk x 256. Block owns n_per consecutive n; LDS table [512][65] covers one
// c-quarter per pass (4 passes). All 4 waves active (2 n per thread).
__global__ __launch_bounds__(256) void k1b_scatter(const float* __restrict__ z,
                                                   const float* __restrict__ out,
                                                   float* __restrict__ ws, int n_per) {
  __shared__ float tab[K_NUM * 65];   // 133,120 B
  float* counts = ws + WS_CNT;
  float* myTab = ws + WS_ACC + (size_t)blockIdx.x * (K_NUM * C_DIM);

  int tid = threadIdx.x;
  int nb = blockIdx.x * n_per;

  for (int pass = 0; pass < 4; ++pass) {
    int cq = pass * 64;
    for (int i = tid; i < K_NUM * 65; i += 256) tab[i] = 0.f;
    __syncthreads();

    for (int nn = tid * 2; nn < n_per; nn += 512) {
      int n0 = nb + nn;
      int i0 = (int)out[OFF_IDX + n0];
      int i1 = (int)out[OFF_IDX + n0 + 1];
      if (pass == 0) {
        unsafeAtomicAdd(&counts[i0], 1.f);
        unsafeAtomicAdd(&counts[i1], 1.f);
      }
      int a0 = i0 * 65, a1 = i1 * 65;
      // n0 even -> n0, n0+1 in one b-plane (planes are 4096-aligned)
      size_t basez = (size_t)(n0 >> 12) * 1048576 + (size_t)(n0 & 4095);
      const float* zp = z + basez + (size_t)cq * 4096;
      #pragma unroll 8
      for (int cl = 0; cl < 64; ++cl) {
        float2 zv = *(const float2*)(zp + (size_t)cl * 4096);
        __hip_atomic_fetch_add(&tab[a0 + cl], zv.x, __ATOMIC_RELAXED,
                               __HIP_MEMORY_SCOPE_WORKGROUP);   // ds_add_f32
        __hip_atomic_fetch_add(&tab[a1 + cl], zv.y, __ATOMIC_RELAXED,
                               __HIP_MEMORY_SCOPE_WORKGROUP);
      }
    }
    __syncthreads();
    // flush c-quarter to private global table: plain coalesced stores
    int cl = tid & 63, kr = tid >> 6;
    for (int k0 = 0; k0 < K_NUM; k0 += 4) {
      int k = k0 + kr;
      myTab[k * C_DIM + cq + cl] = tab[k * 65 + cl];
    }
    __syncthreads();
  }
}

// ---------- kernel 2: cluster-size EMA + smoothing + loss scalar ----------
__global__ __launch_bounds__(512) void k2_cluster(const float* __restrict__ ema_cs,
                                                  float* __restrict__ out,
                                                  float* __restrict__ ws) {
  int k = threadIdx.x;
  float ncs = 0.99f * ema_cs[k] + 0.01f * ws[WS_CNT + k];
  out[OFF_CS + k] = ncs;
  float s = ncs;
  #pragma unroll
  for (int o = 32; o > 0; o >>= 1) s += __shfl_down(s, o, 64);
  __shared__ float ls[8];
  __shared__ float ntot;
  if ((k & 63) == 0) ls[k >> 6] = s;
  __syncthreads();
  if (k == 0) {
    float n = 0.f;
    #pragma unroll
    for (int i = 0; i < 8; ++i) n += ls[i];
    ntot = n;
    out[OFF_LOSS] = 0.5f * ws[WS_LOSS] / 16777216.f;
  }
  __syncthreads();
  float n = ntot;
  ws[WS_SMOOTH + k] = (ncs + 1e-5f) / (n + 0.00512f) * n;
}

// ---------- kernel 3: embed-sum EMA + normalized codebook (sums nblk tables) ----------
__global__ __launch_bounds__(256) void k3_embed(const float* __restrict__ ema_es,
                                                float* __restrict__ out,
                                                const float* __restrict__ ws, int nblk) {
  int k = blockIdx.x, c = threadIdx.x;
  int i = k * C_DIM + c;
  float bs = 0.f;
  for (int t = 0; t < nblk; ++t) bs += ws[WS_ACC + (size_t)t * (K_NUM * C_DIM) + i];
  float es = 0.99f * ema_es[i] + 0.01f * bs;
  out[OFF_ES + i] = es;
  out[OFF_CB + i] = es / ws[WS_SMOOTH + k];
}

extern "C" void kernel_launch(void* const* d_in, const int* in_sizes, int n_in,
                              void* d_out, int out_size, void* d_ws, size_t ws_size,
                              hipStream_t stream) {
  const float* z      = (const float*)d_in[0];
  const float* cb     = (const float*)d_in[1];
  const float* ema_cs = (const float*)d_in[2];
  const float* ema_es = (const float*)d_in[3];
  float* out = (float*)d_out;
  float* ws  = (float*)d_ws;

  // private-table count: as many as ws allows, up to 128 (ws-adaptive, no OOB)
  size_t avail = ws_size / 4;   // floats
  int nblk = 128;
  while (nblk > 8 && (size_t)WS_ACC + (size_t)nblk * (K_NUM * C_DIM) > avail) nblk >>= 1;
  int n_per = 65536 / nblk;

  k0a_prep<<<512, 256, 0, stream>>>(cb, ws);
  k0b_transpose<<<32, 256, 0, stream>>>(cb, ws + WS_CBT);
  k1_gemm<<<512, 256, 0, stream>>>(z, cb, out, ws);
  k1b_scatter<<<nblk, 256, 0, stream>>>(z, out, ws, n_per);
  k2_cluster<<<1, 512, 0, stream>>>(ema_cs, out, ws);
  k3_embed<<<512, 256, 0, stream>>>(ema_es, out, ws, nblk);
}